// Round 4
// baseline (248.196 us; speedup 1.0000x reference)
//
#include <hip/hip_runtime.h>
#include <hip/hip_fp16.h>
#include <math.h>

// ws float layout (header only):
//  [0] E_sum  [1] tr_gp  [2..17] m[16]  [18..33] cs[16]
//  [64..2112)   B[16][128]   (written by k_reduce)
// Scratch lives in the d_out features_pooled region (dead until k_unpool,
// which runs last and overwrites all of it):
//  out0[0      .. 800000)  Ah[N][16] fp16 shadow of assignments (3.2 MB)
//  out0[800000 .. 812512)  csp[GA][16] cluster-size partials (GA=782)
//  out0[825008 .. 861872)  ep[2048][18] edge partials (exactly fits)
//  out0[861872 .. +2048*2048) bp[2048][2048] B partial rows (16.8 MB)
// No atomics anywhere; nothing needs zero-init.

#define WS_ESUM 0
#define WS_TR   1
#define WS_M    2
#define WS_CS   18
#define WS_B    64

#define OFF_AH  0
#define OFF_CSP 800000
#define OFF_EP  825008
#define OFF_BP  861872

#define GE_BLOCKS 2048   // edge role blocks in fused kernel
#define GB_BLOCKS 512    // nodeB role blocks (4 waves -> 2048 partial rows)

typedef int   int4v   __attribute__((ext_vector_type(4)));
typedef float float2v __attribute__((ext_vector_type(2)));
typedef float float4v __attribute__((ext_vector_type(4)));

// ---------------------------------------------------------------- k_assign
// (unchanged — verified: conflict-free padded W layout, 2 nodes/thread)
__global__ __launch_bounds__(256) void k_assign(
    const float* __restrict__ F, const float* __restrict__ W,
    const float* __restrict__ bias, float* __restrict__ A,
    __half* __restrict__ Ah, float* __restrict__ csp, int N) {
  __shared__ float Ws[16 * 144];   // [k][p][36], 9216 B
  __shared__ float csred[4][16];
  int t = threadIdx.x;
#pragma unroll
  for (int i = 0; i < 8; i++) {
    int idx = t + 256 * i;         // 2048 = 16*128 elements
    int k = idx >> 7, r = idx & 127;
    Ws[k * 144 + (r >> 5) * 36 + (r & 31)] = W[idx];
  }
  __syncthreads();

  int p = t & 3;                   // quad part: channels p*32 .. p*32+31
  int slot = t >> 2;               // node slot (0..63)
  int n0 = blockIdx.x * 128 + slot;
  int n1 = n0 + 64;
  bool act0 = (n0 < N), act1 = (n1 < N);
  int n0c = act0 ? n0 : (N - 1);   // clamp: always-in-bounds loads
  int n1c = act1 ? n1 : (N - 1);

  float a0[16], a1[16];
#pragma unroll
  for (int k = 0; k < 16; k++) { a0[k] = 0.f; a1[k] = 0.f; }

  const float4* f0 = (const float4*)(F + (size_t)n0c * 128 + p * 32);
  const float4* f1 = (const float4*)(F + (size_t)n1c * 128 + p * 32);
#pragma unroll
  for (int i = 0; i < 8; i++) {
    float4 x0 = f0[i];
    float4 x1 = f1[i];
#pragma unroll
    for (int k = 0; k < 16; k++) {
      float4 w = *(const float4*)(&Ws[k * 144 + p * 36 + i * 4]);
      a0[k] = fmaf(x0.x, w.x, a0[k]);
      a0[k] = fmaf(x0.y, w.y, a0[k]);
      a0[k] = fmaf(x0.z, w.z, a0[k]);
      a0[k] = fmaf(x0.w, w.w, a0[k]);
      a1[k] = fmaf(x1.x, w.x, a1[k]);
      a1[k] = fmaf(x1.y, w.y, a1[k]);
      a1[k] = fmaf(x1.z, w.z, a1[k]);
      a1[k] = fmaf(x1.w, w.w, a1[k]);
    }
  }

#pragma unroll
  for (int k = 0; k < 16; k++) {
    a0[k] += __shfl_xor(a0[k], 1, 64);
    a0[k] += __shfl_xor(a0[k], 2, 64);
    a1[k] += __shfl_xor(a1[k], 1, 64);
    a1[k] += __shfl_xor(a1[k], 2, 64);
  }

#pragma unroll
  for (int k = 0; k < 16; k++) { a0[k] += bias[k]; a1[k] += bias[k]; }

  float mx0 = a0[0], mx1 = a1[0];
#pragma unroll
  for (int k = 1; k < 16; k++) { mx0 = fmaxf(mx0, a0[k]); mx1 = fmaxf(mx1, a1[k]); }
  float s0 = 0.f, s1 = 0.f;
#pragma unroll
  for (int k = 0; k < 16; k++) {
    a0[k] = __expf(a0[k] - mx0); s0 += a0[k];
    a1[k] = __expf(a1[k] - mx1); s1 += a1[k];
  }
  float inv0 = 1.0f / s0, inv1 = 1.0f / s1;
#pragma unroll
  for (int k = 0; k < 16; k++) { a0[k] *= inv0; a1[k] *= inv1; }

  if (act0)
    ((float4*)(A + (size_t)n0 * 16))[p] =
        make_float4(a0[p * 4 + 0], a0[p * 4 + 1], a0[p * 4 + 2], a0[p * 4 + 3]);
  if (act1)
    ((float4*)(A + (size_t)n1 * 16))[p] =
        make_float4(a1[p * 4 + 0], a1[p * 4 + 1], a1[p * 4 + 2], a1[p * 4 + 3]);

  if (p == 0 && act0) {
    __half2 hh[4];
    hh[0].x = __float2half_rn(a0[0]); hh[0].y = __float2half_rn(a0[1]);
    hh[1].x = __float2half_rn(a0[2]); hh[1].y = __float2half_rn(a0[3]);
    hh[2].x = __float2half_rn(a0[4]); hh[2].y = __float2half_rn(a0[5]);
    hh[3].x = __float2half_rn(a0[6]); hh[3].y = __float2half_rn(a0[7]);
    *(uint4*)(Ah + (size_t)n0 * 16) = *(uint4*)hh;
  } else if (p == 1 && act0) {
    __half2 hh[4];
    hh[0].x = __float2half_rn(a0[8]);  hh[0].y = __float2half_rn(a0[9]);
    hh[1].x = __float2half_rn(a0[10]); hh[1].y = __float2half_rn(a0[11]);
    hh[2].x = __float2half_rn(a0[12]); hh[2].y = __float2half_rn(a0[13]);
    hh[3].x = __float2half_rn(a0[14]); hh[3].y = __float2half_rn(a0[15]);
    *(uint4*)(Ah + (size_t)n0 * 16 + 8) = *(uint4*)hh;
  } else if (p == 2 && act1) {
    __half2 hh[4];
    hh[0].x = __float2half_rn(a1[0]); hh[0].y = __float2half_rn(a1[1]);
    hh[1].x = __float2half_rn(a1[2]); hh[1].y = __float2half_rn(a1[3]);
    hh[2].x = __float2half_rn(a1[4]); hh[2].y = __float2half_rn(a1[5]);
    hh[3].x = __float2half_rn(a1[6]); hh[3].y = __float2half_rn(a1[7]);
    *(uint4*)(Ah + (size_t)n1 * 16) = *(uint4*)hh;
  } else if (p == 3 && act1) {
    __half2 hh[4];
    hh[0].x = __float2half_rn(a1[8]);  hh[0].y = __float2half_rn(a1[9]);
    hh[1].x = __float2half_rn(a1[10]); hh[1].y = __float2half_rn(a1[11]);
    hh[2].x = __float2half_rn(a1[12]); hh[2].y = __float2half_rn(a1[13]);
    hh[3].x = __float2half_rn(a1[14]); hh[3].y = __float2half_rn(a1[15]);
    *(uint4*)(Ah + (size_t)n1 * 16 + 8) = *(uint4*)hh;
  }

  int lane = t & 63, wid = t >> 6;
#pragma unroll
  for (int k = 0; k < 16; k++) {
    float v = 0.f;
    if (p == 0) {
      if (act0) v += a0[k];
      if (act1) v += a1[k];
    }
    for (int off = 32; off; off >>= 1) v += __shfl_xor(v, off, 64);
    if (lane == 0) csred[wid][k] = v;
  }
  __syncthreads();
  if (t < 16)
    csp[(size_t)blockIdx.x * 16 + t] =
        csred[0][t] + csred[1][t] + csred[2][t] + csred[3][t];
}

// ---------------------------------------------------------------- fused
// k_edge_nodeB: block roles interleaved 4 edge : 1 nodeB.
//  edge role v4 (PAIR-SPLIT): 2 lanes per edge; lane parity par covers
//  clusters par*8..par*8+7, gathering only 16 B per node-row. Lanes 2i and
//  2i+1 read consecutive 16B halves of the same 32B-aligned Ah row -> one
//  64B line -> TA coalesces the pair into ONE request: 2 requests/edge
//  (was 4). eS is double-counted (both lanes add v) and scaled 0.5 at the
//  end; tr partials sum correctly under the full xor-reduce (d = d0 + d1);
//  m[8] per parity reduces with xor offsets {32..2} (parity-preserving),
//  lane 0 -> m[0..7], lane 1 -> m[8..15].
//  nodeB role (unchanged): wave owns whole nodes, 32 acc VGPRs, writes its
//  own bp partial row; nt on the 51 MB F stream.
union H2F4 { float4 f4; __half2 h2[4]; };

__device__ __forceinline__ void pair_body(
    const __half* __restrict__ Ah, const int* __restrict__ row,
    const int* __restrict__ col, const float* __restrict__ val,
    int e, int par, float& eS, float& tr, float* m) {
  int   r = __builtin_nontemporal_load(row + e);
  int   c = __builtin_nontemporal_load(col + e);
  float v = __builtin_nontemporal_load(val + e);
  const float4* pc = (const float4*)(Ah + ((size_t)c << 4) + (par << 3));
  const float4* pr = (const float4*)(Ah + ((size_t)r << 4) + (par << 3));
  H2F4 uc, ur;
  uc.f4 = *pc;
  ur.f4 = *pr;
  float cf[8], rf[8];
#pragma unroll
  for (int j = 0; j < 4; j++) {
    float2 f;
    f = __half22float2(uc.h2[j]); cf[2 * j] = f.x; cf[2 * j + 1] = f.y;
    f = __half22float2(ur.h2[j]); rf[2 * j] = f.x; rf[2 * j + 1] = f.y;
  }
  eS += v;                       // both lanes: scaled by 0.5 at the end
  float d = 0.f;
#pragma unroll
  for (int k = 0; k < 8; k++) {
    m[k] = fmaf(v, cf[k], m[k]);
    d = fmaf(rf[k], cf[k], d);
  }
  tr = fmaf(v, d, tr);           // partial dot: pair sums to full under reduce
}

__global__ __launch_bounds__(256, 8) void k_edge_nodeB(
    const int* __restrict__ row, const int* __restrict__ col,
    const float* __restrict__ val, const __half* __restrict__ Ah,
    const float* __restrict__ F, const float* __restrict__ A,
    float* __restrict__ ep, float* __restrict__ bp, int E, int N) {
  __shared__ float red[4][18];
  int b = blockIdx.x;
  int t = threadIdx.x;
  bool isNode = ((b % 5) == 4);

  if (!isNode) {
    // ---------------- edge role: eb in [0, GE_BLOCKS)
    int eb = b - b / 5;
    int par = t & 1;                       // cluster half
    float eS = 0.f, tr = 0.f;
    float m[8];
#pragma unroll
    for (int i = 0; i < 8; i++) m[i] = 0.f;

    int pid = eb * 128 + (t >> 1);         // global pair id
    const int P = GE_BLOCKS * 128;         // pairs total (262144)
    int e = pid;
    for (; e + P < E; e += 2 * P) {
      pair_body(Ah, row, col, val, e, par, eS, tr, m);
      pair_body(Ah, row, col, val, e + P, par, eS, tr, m);
    }
    for (; e < E; e += P)
      pair_body(Ah, row, col, val, e, par, eS, tr, m);

    // parity-preserving reduce for m (offsets 32..2)
#pragma unroll
    for (int i = 0; i < 8; i++) {
      float v = m[i];
      v += __shfl_xor(v, 32, 64);
      v += __shfl_xor(v, 16, 64);
      v += __shfl_xor(v, 8, 64);
      v += __shfl_xor(v, 4, 64);
      v += __shfl_xor(v, 2, 64);
      m[i] = v;
    }
    // full reduce for eS, tr
    for (int off = 32; off; off >>= 1) {
      eS += __shfl_xor(eS, off, 64);
      tr += __shfl_xor(tr, off, 64);
    }
    int lane = t & 63, wid = t >> 6;
    if (lane == 0) {
      red[wid][0] = eS * 0.5f;             // each edge counted by both lanes
      red[wid][1] = tr;
#pragma unroll
      for (int i = 0; i < 8; i++) red[wid][2 + i] = m[i];
    } else if (lane == 1) {
#pragma unroll
      for (int i = 0; i < 8; i++) red[wid][10 + i] = m[i];
    }
    __syncthreads();
    if (t < 18)
      ep[(size_t)eb * 18 + t] =
          red[0][t] + red[1][t] + red[2][t] + red[3][t];
  } else {
    // ---------------- nodeB role: nb in [0, GB_BLOCKS)
    int nb = b / 5;
    int lane = t & 63;             // channel pair: c = 2*lane, 2*lane+1
    int wid = t >> 6;              // 0..3 — wave owns its own node stream

    float2 acc[16];
#pragma unroll
    for (int k = 0; k < 16; k++) acc[k] = make_float2(0.f, 0.f);

    const float2v* F2 = (const float2v*)F;
    const float4* A4 = (const float4*)A;
    const int stride = GB_BLOCKS * 4;
    for (int n = nb * 4 + wid; n < N; n += stride) {
      float2v f = __builtin_nontemporal_load(&F2[(size_t)n * 64 + lane]);
      float4 a0 = A4[(size_t)n * 4 + 0];
      float4 a1 = A4[(size_t)n * 4 + 1];
      float4 a2 = A4[(size_t)n * 4 + 2];
      float4 a3 = A4[(size_t)n * 4 + 3];
      float av[16] = {a0.x, a0.y, a0.z, a0.w, a1.x, a1.y, a1.z, a1.w,
                      a2.x, a2.y, a2.z, a2.w, a3.x, a3.y, a3.z, a3.w};
#pragma unroll
      for (int k = 0; k < 16; k++) {
        acc[k].x = fmaf(av[k], f.x, acc[k].x);
        acc[k].y = fmaf(av[k], f.y, acc[k].y);
      }
    }
    // each wave writes its own partial row — no reduction needed
    float* myrow = bp + (size_t)(nb * 4 + wid) * 2048;
#pragma unroll
    for (int k = 0; k < 16; k++)
      *(float2*)&myrow[k * 128 + lane * 2] = acc[k];
  }
}

// ---------------------------------------------------------------- k_reduce
// 258 blocks. GB = 2048 partial rows. (unchanged)
__global__ __launch_bounds__(256) void k_reduce(
    const float* __restrict__ csp, const float* __restrict__ ep,
    const float* __restrict__ bp, float* __restrict__ ws,
    int GA, int GE, int GB) {
  __shared__ float L[256];
  int t = threadIdx.x;
  int b = blockIdx.x;
  if (b < 256) {
    int cell = b * 8 + (t & 7);
    int seg = t >> 3;                      // 0..31
    float s0 = 0.f, s1 = 0.f, s2 = 0.f, s3 = 0.f;
    int g = seg;
    for (; g + 96 < GB; g += 128) {
      s0 += bp[(size_t)g * 2048 + cell];
      s1 += bp[(size_t)(g + 32) * 2048 + cell];
      s2 += bp[(size_t)(g + 64) * 2048 + cell];
      s3 += bp[(size_t)(g + 96) * 2048 + cell];
    }
    for (; g < GB; g += 32) s0 += bp[(size_t)g * 2048 + cell];
    L[t] = (s0 + s1) + (s2 + s3);
    __syncthreads();
    if (t < 8) {
      float tot = 0.f;
#pragma unroll
      for (int s = 0; s < 32; s++) tot += L[s * 8 + t];
      ws[WS_B + b * 8 + t] = tot;
    }
  } else if (b == 256) {
    int n = GE * 18;
    float s0 = 0.f, s1 = 0.f, s2 = 0.f, s3 = 0.f;
    if (t < 252) {
      int f = t;
      for (; f + 756 < n; f += 1008) {
        s0 += ep[f]; s1 += ep[f + 252]; s2 += ep[f + 504]; s3 += ep[f + 756];
      }
      for (; f < n; f += 252) s0 += ep[f];
    }
    L[t] = (s0 + s1) + (s2 + s3);
    __syncthreads();
    if (t < 18) {
      float tot = 0.f;
#pragma unroll
      for (int j = 0; j < 14; j++) tot += L[j * 18 + t];
      ws[t] = tot;                        // E_sum, tr, m[16]
    }
  } else {
    int n = GA * 16;
    float s0 = 0.f, s1 = 0.f, s2 = 0.f, s3 = 0.f;
    int f = t;
    for (; f + 768 < n; f += 1024) {
      s0 += csp[f]; s1 += csp[f + 256]; s2 += csp[f + 512]; s3 += csp[f + 768];
    }
    for (; f < n; f += 256) s0 += csp[f];
    L[t] = (s0 + s1) + (s2 + s3);
    __syncthreads();
    if (t < 16) {
      float tot = 0.f;
#pragma unroll
      for (int j = 0; j < 16; j++) tot += L[j * 16 + t];
      ws[WS_CS + t] = tot;
    }
  }
}

// ---------------------------------------------------------------- k_unpool
// out[n,c] = sum_k A[n,k] * P2[k,c]   (runs LAST — overwrites scratch)
// finalize folded in; P2 in registers; nontemporal float4 stores.
__global__ __launch_bounds__(256) void k_unpool(
    const float* __restrict__ A, float* __restrict__ ws,
    float* __restrict__ out, float* __restrict__ loss_out, int N) {
  __shared__ float Ps[2048];
  __shared__ float invcs[16];
  int t = threadIdx.x;
  if (t < 16) invcs[t] = 1.0f / ws[WS_CS + t];
  __syncthreads();
  const float scale = 1.0507009873554805f;
  const float alpha = 1.6732632423543772f;
#pragma unroll
  for (int i = 0; i < 8; i++) {
    int idx = t + 256 * i;
    int k = idx >> 7;
    float x = ws[WS_B + idx] * invcs[k];
    float s = (x > 0.f) ? scale * x : scale * alpha * expm1f(x);
    Ps[idx] = s * invcs[k];
  }
  __syncthreads();

  if (blockIdx.x == 0 && t == 0) {
    float Es = ws[WS_ESUM], tr = ws[WS_TR];
    float m2 = 0.f;
#pragma unroll
    for (int i = 0; i < 16; i++) m2 += ws[WS_M + i] * ws[WS_M + i];
    float spectral = -(tr - m2 / (2.0f * Es)) / (2.0f * Es);
    float coll = 0.f;
    float tgt = (float)N / 16.0f;
#pragma unroll
    for (int i = 0; i < 16; i++) coll += fabsf(ws[WS_CS + i] - tgt);
    coll = coll / (float)N * (4.0f / 3.0f / 2.0f);  // sk/(sk-1)/2, sk=4
    loss_out[0] = spectral + coll;
  }

  int c4 = (t & 31) << 2;          // channel base (0,4,...,124)
  int sub = t >> 5;                // 0..7 (node within group)
  float4 pk[16];
#pragma unroll
  for (int k = 0; k < 16; k++) pk[k] = *(const float4*)&Ps[k * 128 + c4];

  int stride = gridDim.x * 8;
  for (int n = blockIdx.x * 8 + sub; n < N; n += stride) {
    const float4* a4 = (const float4*)(A + (size_t)n * 16);
    float4 a0 = a4[0], a1 = a4[1], a2 = a4[2], a3 = a4[3];
    float av[16] = {a0.x, a0.y, a0.z, a0.w, a1.x, a1.y, a1.z, a1.w,
                    a2.x, a2.y, a2.z, a2.w, a3.x, a3.y, a3.z, a3.w};
    float4v s = {0.f, 0.f, 0.f, 0.f};
#pragma unroll
    for (int k = 0; k < 16; k++) {
      s.x = fmaf(av[k], pk[k].x, s.x);
      s.y = fmaf(av[k], pk[k].y, s.y);
      s.z = fmaf(av[k], pk[k].z, s.z);
      s.w = fmaf(av[k], pk[k].w, s.w);
    }
    __builtin_nontemporal_store(s, (float4v*)(out + (size_t)n * 128 + c4));
  }
}

// ----------------------------------------------------------------
extern "C" void kernel_launch(void* const* d_in, const int* in_sizes, int n_in,
                              void* d_out, int out_size, void* d_ws, size_t ws_size,
                              hipStream_t stream) {
  const float* F    = (const float*)d_in[0];  // [N,128]
  const int*   erow = (const int*)d_in[1];    // [E]
  const int*   ecol = (const int*)d_in[2];    // [E]
  const float* eval_= (const float*)d_in[3];  // [E]
  const float* W    = (const float*)d_in[4];  // [16,128]
  const float* bias = (const float*)d_in[5];  // [16]

  int N = in_sizes[0] / 128;
  int E = in_sizes[1];

  float* out0 = (float*)d_out;                 // features_pooled [N,128]
  float* A    = out0 + (size_t)N * 128;        // assignments [N,16]
  float* loss = A + (size_t)N * 16;            // scalar
  float* ws   = (float*)d_ws;

  int GA = (N + 127) / 128;                    // k_assign grid (782)
  int GE = GE_BLOCKS;                          // 2048 edge-role blocks
  int GBp = GB_BLOCKS * 4;                     // 2048 bp partial rows

  // scratch inside the (not-yet-written) features_pooled output region
  __half* Ah  = (__half*)(out0 + OFF_AH);      // [N][16] fp16, 3.2 MB
  float*  csp = out0 + OFF_CSP;                // [GA][16]
  float*  ep  = out0 + OFF_EP;                 // [2048][18]
  float*  bp  = out0 + OFF_BP;                 // [2048][2048], 16.8 MB

  k_assign<<<GA, 256, 0, stream>>>(F, W, bias, A, Ah, csp, N);
  k_edge_nodeB<<<GE_BLOCKS + GB_BLOCKS, 256, 0, stream>>>(
      erow, ecol, eval_, Ah, F, A, ep, bp, E, N);
  k_reduce<<<258, 256, 0, stream>>>(csp, ep, bp, ws, GA, GE, GBp);
  k_unpool<<<1280, 256, 0, stream>>>(A, ws, out0, loss, N);
}

// Round 5
// 246.657 us; speedup vs baseline: 1.0062x; 1.0062x over previous
//
#include <hip/hip_runtime.h>
#include <hip/hip_fp16.h>
#include <math.h>

// ws float layout (header only):
//  [0] E_sum  [1] tr_gp  [2..17] m[16]  [18..33] cs[16]
//  [64..2112)   B[16][128]   (written by k_reduce)
// Scratch lives in the d_out features_pooled region (dead until k_unpool,
// which runs last and overwrites all of it):
//  out0[0      .. 800000)  Ah[N][16] fp16 shadow of assignments (3.2 MB)
//  out0[800000 .. 812512)  csp[GA][16] cluster-size partials (GA=782)
//  out0[825008 .. 861872)  ep[2048][18] edge partials (exactly fits)
//  out0[861872 .. +2048*2048) bp[2048][2048] B partial rows (16.8 MB)
// No atomics anywhere; nothing needs zero-init.

#define WS_ESUM 0
#define WS_TR   1
#define WS_M    2
#define WS_CS   18
#define WS_B    64

#define OFF_AH  0
#define OFF_CSP 800000
#define OFF_EP  825008
#define OFF_BP  861872

#define GE_BLOCKS 2048   // edge role blocks in fused kernel
#define GB_BLOCKS 512    // nodeB role blocks (4 waves -> 2048 partial rows)

typedef int   int4v   __attribute__((ext_vector_type(4)));
typedef float float2v __attribute__((ext_vector_type(2)));
typedef float float4v __attribute__((ext_vector_type(4)));

// ---------------------------------------------------------------- k_assign
// (unchanged — verified: conflict-free padded W layout, 2 nodes/thread)
__global__ __launch_bounds__(256) void k_assign(
    const float* __restrict__ F, const float* __restrict__ W,
    const float* __restrict__ bias, float* __restrict__ A,
    __half* __restrict__ Ah, float* __restrict__ csp, int N) {
  __shared__ float Ws[16 * 144];   // [k][p][36], 9216 B
  __shared__ float csred[4][16];
  int t = threadIdx.x;
#pragma unroll
  for (int i = 0; i < 8; i++) {
    int idx = t + 256 * i;         // 2048 = 16*128 elements
    int k = idx >> 7, r = idx & 127;
    Ws[k * 144 + (r >> 5) * 36 + (r & 31)] = W[idx];
  }
  __syncthreads();

  int p = t & 3;                   // quad part: channels p*32 .. p*32+31
  int slot = t >> 2;               // node slot (0..63)
  int n0 = blockIdx.x * 128 + slot;
  int n1 = n0 + 64;
  bool act0 = (n0 < N), act1 = (n1 < N);
  int n0c = act0 ? n0 : (N - 1);   // clamp: always-in-bounds loads
  int n1c = act1 ? n1 : (N - 1);

  float a0[16], a1[16];
#pragma unroll
  for (int k = 0; k < 16; k++) { a0[k] = 0.f; a1[k] = 0.f; }

  const float4* f0 = (const float4*)(F + (size_t)n0c * 128 + p * 32);
  const float4* f1 = (const float4*)(F + (size_t)n1c * 128 + p * 32);
#pragma unroll
  for (int i = 0; i < 8; i++) {
    float4 x0 = f0[i];
    float4 x1 = f1[i];
#pragma unroll
    for (int k = 0; k < 16; k++) {
      float4 w = *(const float4*)(&Ws[k * 144 + p * 36 + i * 4]);
      a0[k] = fmaf(x0.x, w.x, a0[k]);
      a0[k] = fmaf(x0.y, w.y, a0[k]);
      a0[k] = fmaf(x0.z, w.z, a0[k]);
      a0[k] = fmaf(x0.w, w.w, a0[k]);
      a1[k] = fmaf(x1.x, w.x, a1[k]);
      a1[k] = fmaf(x1.y, w.y, a1[k]);
      a1[k] = fmaf(x1.z, w.z, a1[k]);
      a1[k] = fmaf(x1.w, w.w, a1[k]);
    }
  }

#pragma unroll
  for (int k = 0; k < 16; k++) {
    a0[k] += __shfl_xor(a0[k], 1, 64);
    a0[k] += __shfl_xor(a0[k], 2, 64);
    a1[k] += __shfl_xor(a1[k], 1, 64);
    a1[k] += __shfl_xor(a1[k], 2, 64);
  }

#pragma unroll
  for (int k = 0; k < 16; k++) { a0[k] += bias[k]; a1[k] += bias[k]; }

  float mx0 = a0[0], mx1 = a1[0];
#pragma unroll
  for (int k = 1; k < 16; k++) { mx0 = fmaxf(mx0, a0[k]); mx1 = fmaxf(mx1, a1[k]); }
  float s0 = 0.f, s1 = 0.f;
#pragma unroll
  for (int k = 0; k < 16; k++) {
    a0[k] = __expf(a0[k] - mx0); s0 += a0[k];
    a1[k] = __expf(a1[k] - mx1); s1 += a1[k];
  }
  float inv0 = 1.0f / s0, inv1 = 1.0f / s1;
#pragma unroll
  for (int k = 0; k < 16; k++) { a0[k] *= inv0; a1[k] *= inv1; }

  if (act0)
    ((float4*)(A + (size_t)n0 * 16))[p] =
        make_float4(a0[p * 4 + 0], a0[p * 4 + 1], a0[p * 4 + 2], a0[p * 4 + 3]);
  if (act1)
    ((float4*)(A + (size_t)n1 * 16))[p] =
        make_float4(a1[p * 4 + 0], a1[p * 4 + 1], a1[p * 4 + 2], a1[p * 4 + 3]);

  if (p == 0 && act0) {
    __half2 hh[4];
    hh[0].x = __float2half_rn(a0[0]); hh[0].y = __float2half_rn(a0[1]);
    hh[1].x = __float2half_rn(a0[2]); hh[1].y = __float2half_rn(a0[3]);
    hh[2].x = __float2half_rn(a0[4]); hh[2].y = __float2half_rn(a0[5]);
    hh[3].x = __float2half_rn(a0[6]); hh[3].y = __float2half_rn(a0[7]);
    *(uint4*)(Ah + (size_t)n0 * 16) = *(uint4*)hh;
  } else if (p == 1 && act0) {
    __half2 hh[4];
    hh[0].x = __float2half_rn(a0[8]);  hh[0].y = __float2half_rn(a0[9]);
    hh[1].x = __float2half_rn(a0[10]); hh[1].y = __float2half_rn(a0[11]);
    hh[2].x = __float2half_rn(a0[12]); hh[2].y = __float2half_rn(a0[13]);
    hh[3].x = __float2half_rn(a0[14]); hh[3].y = __float2half_rn(a0[15]);
    *(uint4*)(Ah + (size_t)n0 * 16 + 8) = *(uint4*)hh;
  } else if (p == 2 && act1) {
    __half2 hh[4];
    hh[0].x = __float2half_rn(a1[0]); hh[0].y = __float2half_rn(a1[1]);
    hh[1].x = __float2half_rn(a1[2]); hh[1].y = __float2half_rn(a1[3]);
    hh[2].x = __float2half_rn(a1[4]); hh[2].y = __float2half_rn(a1[5]);
    hh[3].x = __float2half_rn(a1[6]); hh[3].y = __float2half_rn(a1[7]);
    *(uint4*)(Ah + (size_t)n1 * 16) = *(uint4*)hh;
  } else if (p == 3 && act1) {
    __half2 hh[4];
    hh[0].x = __float2half_rn(a1[8]);  hh[0].y = __float2half_rn(a1[9]);
    hh[1].x = __float2half_rn(a1[10]); hh[1].y = __float2half_rn(a1[11]);
    hh[2].x = __float2half_rn(a1[12]); hh[2].y = __float2half_rn(a1[13]);
    hh[3].x = __float2half_rn(a1[14]); hh[3].y = __float2half_rn(a1[15]);
    *(uint4*)(Ah + (size_t)n1 * 16 + 8) = *(uint4*)hh;
  }

  int lane = t & 63, wid = t >> 6;
#pragma unroll
  for (int k = 0; k < 16; k++) {
    float v = 0.f;
    if (p == 0) {
      if (act0) v += a0[k];
      if (act1) v += a1[k];
    }
    for (int off = 32; off; off >>= 1) v += __shfl_xor(v, off, 64);
    if (lane == 0) csred[wid][k] = v;
  }
  __syncthreads();
  if (t < 16)
    csp[(size_t)blockIdx.x * 16 + t] =
        csred[0][t] + csred[1][t] + csred[2][t] + csred[3][t];
}

// ---------------------------------------------------------------- fused
// k_edge_nodeB: block roles interleaved 4 edge : 1 nodeB.
//  edge role v5 (PAIR-SPLIT + BATCH-4 PIPELINE): 2 lanes per edge (parity
//  par covers clusters par*8..+7, 16B gather per node-row). Per lane:
//  batch of 4 edges -> issue all 8 gathers (32 VGPR buffer), then prefetch
//  the NEXT batch's 12 index scalars (independent -> issues under the
//  gathers), then compute. In-flight gathers per wave: 2 -> 8.
//  __launch_bounds__(256,6): VGPR cap ~85, 6 blocks/CU — trades 2 waves
//  for 4x gather MLP (round-1 lesson: don't let VGPR kill the wave count;
//  round-4 lesson: lane-request count, not wave-instruction count, is
//  what the TA charges).
//  nodeB role (unchanged): wave owns whole nodes, writes its own bp row.
union H2F4 { float4 f4; __half2 h2[4]; };

__device__ __forceinline__ void pair_body(
    const __half* __restrict__ Ah, const int* __restrict__ row,
    const int* __restrict__ col, const float* __restrict__ val,
    int e, int par, float& eS, float& tr, float* m) {
  int   r = __builtin_nontemporal_load(row + e);
  int   c = __builtin_nontemporal_load(col + e);
  float v = __builtin_nontemporal_load(val + e);
  const float4* pc = (const float4*)(Ah + ((size_t)c << 4) + (par << 3));
  const float4* pr = (const float4*)(Ah + ((size_t)r << 4) + (par << 3));
  H2F4 uc, ur;
  uc.f4 = *pc;
  ur.f4 = *pr;
  float cf[8], rf[8];
#pragma unroll
  for (int j = 0; j < 4; j++) {
    float2 f;
    f = __half22float2(uc.h2[j]); cf[2 * j] = f.x; cf[2 * j + 1] = f.y;
    f = __half22float2(ur.h2[j]); rf[2 * j] = f.x; rf[2 * j + 1] = f.y;
  }
  eS += v;
  float d = 0.f;
#pragma unroll
  for (int k = 0; k < 8; k++) {
    m[k] = fmaf(v, cf[k], m[k]);
    d = fmaf(rf[k], cf[k], d);
  }
  tr = fmaf(v, d, tr);
}

__global__ __launch_bounds__(256, 6) void k_edge_nodeB(
    const int* __restrict__ row, const int* __restrict__ col,
    const float* __restrict__ val, const __half* __restrict__ Ah,
    const float* __restrict__ F, const float* __restrict__ A,
    float* __restrict__ ep, float* __restrict__ bp, int E, int N) {
  __shared__ float red[4][18];
  int b = blockIdx.x;
  int t = threadIdx.x;
  bool isNode = ((b % 5) == 4);

  if (!isNode) {
    // ---------------- edge role: eb in [0, GE_BLOCKS)
    int eb = b - b / 5;
    int par = t & 1;                       // cluster half
    float eS = 0.f, tr = 0.f;
    float m[8];
#pragma unroll
    for (int i = 0; i < 8; i++) m[i] = 0.f;

    const int P = GE_BLOCKS * 128;         // pairs total (262144)
    int pid = eb * 128 + (t >> 1);         // global pair id
    const size_t hoff = (size_t)(par << 3);

    int e = pid;
    if (e + 3 * P < E) {
      // preload batch-0 indices
      int   r0 = __builtin_nontemporal_load(row + e);
      int   c0 = __builtin_nontemporal_load(col + e);
      float v0 = __builtin_nontemporal_load(val + e);
      int   r1 = __builtin_nontemporal_load(row + e + P);
      int   c1 = __builtin_nontemporal_load(col + e + P);
      float v1 = __builtin_nontemporal_load(val + e + P);
      int   r2 = __builtin_nontemporal_load(row + e + 2 * P);
      int   c2 = __builtin_nontemporal_load(col + e + 2 * P);
      float v2 = __builtin_nontemporal_load(val + e + 2 * P);
      int   r3 = __builtin_nontemporal_load(row + e + 3 * P);
      int   c3 = __builtin_nontemporal_load(col + e + 3 * P);
      float v3 = __builtin_nontemporal_load(val + e + 3 * P);
      while (true) {
        // 1) issue all 8 gathers for the current batch
        H2F4 gr0, gc0, gr1, gc1, gr2, gc2, gr3, gc3;
        gr0.f4 = *(const float4*)(Ah + ((size_t)r0 << 4) + hoff);
        gc0.f4 = *(const float4*)(Ah + ((size_t)c0 << 4) + hoff);
        gr1.f4 = *(const float4*)(Ah + ((size_t)r1 << 4) + hoff);
        gc1.f4 = *(const float4*)(Ah + ((size_t)c1 << 4) + hoff);
        gr2.f4 = *(const float4*)(Ah + ((size_t)r2 << 4) + hoff);
        gc2.f4 = *(const float4*)(Ah + ((size_t)c2 << 4) + hoff);
        gr3.f4 = *(const float4*)(Ah + ((size_t)r3 << 4) + hoff);
        gc3.f4 = *(const float4*)(Ah + ((size_t)c3 << 4) + hoff);

        // 2) prefetch next batch's indices (independent of the gathers;
        //    r/c regs are free after address issue, v needs fresh regs)
        int en = e + 4 * P;
        bool more = (en + 3 * P < E);
        int pb = more ? en : e;            // last iter: harmless reload
        r0 = __builtin_nontemporal_load(row + pb);
        c0 = __builtin_nontemporal_load(col + pb);
        float w0 = __builtin_nontemporal_load(val + pb);
        r1 = __builtin_nontemporal_load(row + pb + P);
        c1 = __builtin_nontemporal_load(col + pb + P);
        float w1 = __builtin_nontemporal_load(val + pb + P);
        r2 = __builtin_nontemporal_load(row + pb + 2 * P);
        c2 = __builtin_nontemporal_load(col + pb + 2 * P);
        float w2 = __builtin_nontemporal_load(val + pb + 2 * P);
        r3 = __builtin_nontemporal_load(row + pb + 3 * P);
        c3 = __builtin_nontemporal_load(col + pb + 3 * P);
        float w3 = __builtin_nontemporal_load(val + pb + 3 * P);

        // 3) compute the 4 edges
        {
          float cf[8], rf[8];
#pragma unroll
          for (int q = 0; q < 4; q++) {
            float2 f;
            f = __half22float2(gc0.h2[q]); cf[2*q] = f.x; cf[2*q+1] = f.y;
            f = __half22float2(gr0.h2[q]); rf[2*q] = f.x; rf[2*q+1] = f.y;
          }
          eS += v0;
          float d = 0.f;
#pragma unroll
          for (int k = 0; k < 8; k++) {
            m[k] = fmaf(v0, cf[k], m[k]);
            d = fmaf(rf[k], cf[k], d);
          }
          tr = fmaf(v0, d, tr);
        }
        {
          float cf[8], rf[8];
#pragma unroll
          for (int q = 0; q < 4; q++) {
            float2 f;
            f = __half22float2(gc1.h2[q]); cf[2*q] = f.x; cf[2*q+1] = f.y;
            f = __half22float2(gr1.h2[q]); rf[2*q] = f.x; rf[2*q+1] = f.y;
          }
          eS += v1;
          float d = 0.f;
#pragma unroll
          for (int k = 0; k < 8; k++) {
            m[k] = fmaf(v1, cf[k], m[k]);
            d = fmaf(rf[k], cf[k], d);
          }
          tr = fmaf(v1, d, tr);
        }
        {
          float cf[8], rf[8];
#pragma unroll
          for (int q = 0; q < 4; q++) {
            float2 f;
            f = __half22float2(gc2.h2[q]); cf[2*q] = f.x; cf[2*q+1] = f.y;
            f = __half22float2(gr2.h2[q]); rf[2*q] = f.x; rf[2*q+1] = f.y;
          }
          eS += v2;
          float d = 0.f;
#pragma unroll
          for (int k = 0; k < 8; k++) {
            m[k] = fmaf(v2, cf[k], m[k]);
            d = fmaf(rf[k], cf[k], d);
          }
          tr = fmaf(v2, d, tr);
        }
        {
          float cf[8], rf[8];
#pragma unroll
          for (int q = 0; q < 4; q++) {
            float2 f;
            f = __half22float2(gc3.h2[q]); cf[2*q] = f.x; cf[2*q+1] = f.y;
            f = __half22float2(gr3.h2[q]); rf[2*q] = f.x; rf[2*q+1] = f.y;
          }
          eS += v3;
          float d = 0.f;
#pragma unroll
          for (int k = 0; k < 8; k++) {
            m[k] = fmaf(v3, cf[k], m[k]);
            d = fmaf(rf[k], cf[k], d);
          }
          tr = fmaf(v3, d, tr);
        }

        v0 = w0; v1 = w1; v2 = w2; v3 = w3;
        e = en;
        if (!more) break;
      }
    }
    // tail: < 4 remaining passes
    for (; e < E; e += P)
      pair_body(Ah, row, col, val, e, par, eS, tr, m);

    // parity-preserving reduce for m (offsets 32..2)
#pragma unroll
    for (int i = 0; i < 8; i++) {
      float v = m[i];
      v += __shfl_xor(v, 32, 64);
      v += __shfl_xor(v, 16, 64);
      v += __shfl_xor(v, 8, 64);
      v += __shfl_xor(v, 4, 64);
      v += __shfl_xor(v, 2, 64);
      m[i] = v;
    }
    // full reduce for eS, tr
    for (int off = 32; off; off >>= 1) {
      eS += __shfl_xor(eS, off, 64);
      tr += __shfl_xor(tr, off, 64);
    }
    int lane = t & 63, wid = t >> 6;
    if (lane == 0) {
      red[wid][0] = eS * 0.5f;             // each edge counted by both lanes
      red[wid][1] = tr;
#pragma unroll
      for (int i = 0; i < 8; i++) red[wid][2 + i] = m[i];
    } else if (lane == 1) {
#pragma unroll
      for (int i = 0; i < 8; i++) red[wid][10 + i] = m[i];
    }
    __syncthreads();
    if (t < 18)
      ep[(size_t)eb * 18 + t] =
          red[0][t] + red[1][t] + red[2][t] + red[3][t];
  } else {
    // ---------------- nodeB role: nb in [0, GB_BLOCKS)
    int nb = b / 5;
    int lane = t & 63;             // channel pair: c = 2*lane, 2*lane+1
    int wid = t >> 6;              // 0..3 — wave owns its own node stream

    float2 acc[16];
#pragma unroll
    for (int k = 0; k < 16; k++) acc[k] = make_float2(0.f, 0.f);

    const float2v* F2 = (const float2v*)F;
    const float4* A4 = (const float4*)A;
    const int stride = GB_BLOCKS * 4;
    for (int n = nb * 4 + wid; n < N; n += stride) {
      float2v f = __builtin_nontemporal_load(&F2[(size_t)n * 64 + lane]);
      float4 a0 = A4[(size_t)n * 4 + 0];
      float4 a1 = A4[(size_t)n * 4 + 1];
      float4 a2 = A4[(size_t)n * 4 + 2];
      float4 a3 = A4[(size_t)n * 4 + 3];
      float av[16] = {a0.x, a0.y, a0.z, a0.w, a1.x, a1.y, a1.z, a1.w,
                      a2.x, a2.y, a2.z, a2.w, a3.x, a3.y, a3.z, a3.w};
#pragma unroll
      for (int k = 0; k < 16; k++) {
        acc[k].x = fmaf(av[k], f.x, acc[k].x);
        acc[k].y = fmaf(av[k], f.y, acc[k].y);
      }
    }
    // each wave writes its own partial row — no reduction needed
    float* myrow = bp + (size_t)(nb * 4 + wid) * 2048;
#pragma unroll
    for (int k = 0; k < 16; k++)
      *(float2*)&myrow[k * 128 + lane * 2] = acc[k];
  }
}

// ---------------------------------------------------------------- k_reduce
// 258 blocks. GB = 2048 partial rows. (unchanged)
__global__ __launch_bounds__(256) void k_reduce(
    const float* __restrict__ csp, const float* __restrict__ ep,
    const float* __restrict__ bp, float* __restrict__ ws,
    int GA, int GE, int GB) {
  __shared__ float L[256];
  int t = threadIdx.x;
  int b = blockIdx.x;
  if (b < 256) {
    int cell = b * 8 + (t & 7);
    int seg = t >> 3;                      // 0..31
    float s0 = 0.f, s1 = 0.f, s2 = 0.f, s3 = 0.f;
    int g = seg;
    for (; g + 96 < GB; g += 128) {
      s0 += bp[(size_t)g * 2048 + cell];
      s1 += bp[(size_t)(g + 32) * 2048 + cell];
      s2 += bp[(size_t)(g + 64) * 2048 + cell];
      s3 += bp[(size_t)(g + 96) * 2048 + cell];
    }
    for (; g < GB; g += 32) s0 += bp[(size_t)g * 2048 + cell];
    L[t] = (s0 + s1) + (s2 + s3);
    __syncthreads();
    if (t < 8) {
      float tot = 0.f;
#pragma unroll
      for (int s = 0; s < 32; s++) tot += L[s * 8 + t];
      ws[WS_B + b * 8 + t] = tot;
    }
  } else if (b == 256) {
    int n = GE * 18;
    float s0 = 0.f, s1 = 0.f, s2 = 0.f, s3 = 0.f;
    if (t < 252) {
      int f = t;
      for (; f + 756 < n; f += 1008) {
        s0 += ep[f]; s1 += ep[f + 252]; s2 += ep[f + 504]; s3 += ep[f + 756];
      }
      for (; f < n; f += 252) s0 += ep[f];
    }
    L[t] = (s0 + s1) + (s2 + s3);
    __syncthreads();
    if (t < 18) {
      float tot = 0.f;
#pragma unroll
      for (int j = 0; j < 14; j++) tot += L[j * 18 + t];
      ws[t] = tot;                        // E_sum, tr, m[16]
    }
  } else {
    int n = GA * 16;
    float s0 = 0.f, s1 = 0.f, s2 = 0.f, s3 = 0.f;
    int f = t;
    for (; f + 768 < n; f += 1024) {
      s0 += csp[f]; s1 += csp[f + 256]; s2 += csp[f + 512]; s3 += csp[f + 768];
    }
    for (; f < n; f += 256) s0 += csp[f];
    L[t] = (s0 + s1) + (s2 + s3);
    __syncthreads();
    if (t < 16) {
      float tot = 0.f;
#pragma unroll
      for (int j = 0; j < 16; j++) tot += L[j * 16 + t];
      ws[WS_CS + t] = tot;
    }
  }
}

// ---------------------------------------------------------------- k_unpool
// out[n,c] = sum_k A[n,k] * P2[k,c]   (runs LAST — overwrites scratch)
// finalize folded in; P2 in registers; nontemporal float4 stores.
__global__ __launch_bounds__(256) void k_unpool(
    const float* __restrict__ A, float* __restrict__ ws,
    float* __restrict__ out, float* __restrict__ loss_out, int N) {
  __shared__ float Ps[2048];
  __shared__ float invcs[16];
  int t = threadIdx.x;
  if (t < 16) invcs[t] = 1.0f / ws[WS_CS + t];
  __syncthreads();
  const float scale = 1.0507009873554805f;
  const float alpha = 1.6732632423543772f;
#pragma unroll
  for (int i = 0; i < 8; i++) {
    int idx = t + 256 * i;
    int k = idx >> 7;
    float x = ws[WS_B + idx] * invcs[k];
    float s = (x > 0.f) ? scale * x : scale * alpha * expm1f(x);
    Ps[idx] = s * invcs[k];
  }
  __syncthreads();

  if (blockIdx.x == 0 && t == 0) {
    float Es = ws[WS_ESUM], tr = ws[WS_TR];
    float m2 = 0.f;
#pragma unroll
    for (int i = 0; i < 16; i++) m2 += ws[WS_M + i] * ws[WS_M + i];
    float spectral = -(tr - m2 / (2.0f * Es)) / (2.0f * Es);
    float coll = 0.f;
    float tgt = (float)N / 16.0f;
#pragma unroll
    for (int i = 0; i < 16; i++) coll += fabsf(ws[WS_CS + i] - tgt);
    coll = coll / (float)N * (4.0f / 3.0f / 2.0f);  // sk/(sk-1)/2, sk=4
    loss_out[0] = spectral + coll;
  }

  int c4 = (t & 31) << 2;          // channel base (0,4,...,124)
  int sub = t >> 5;                // 0..7 (node within group)
  float4 pk[16];
#pragma unroll
  for (int k = 0; k < 16; k++) pk[k] = *(const float4*)&Ps[k * 128 + c4];

  int stride = gridDim.x * 8;
  for (int n = blockIdx.x * 8 + sub; n < N; n += stride) {
    const float4* a4 = (const float4*)(A + (size_t)n * 16);
    float4 a0 = a4[0], a1 = a4[1], a2 = a4[2], a3 = a4[3];
    float av[16] = {a0.x, a0.y, a0.z, a0.w, a1.x, a1.y, a1.z, a1.w,
                    a2.x, a2.y, a2.z, a2.w, a3.x, a3.y, a3.z, a3.w};
    float4v s = {0.f, 0.f, 0.f, 0.f};
#pragma unroll
    for (int k = 0; k < 16; k++) {
      s.x = fmaf(av[k], pk[k].x, s.x);
      s.y = fmaf(av[k], pk[k].y, s.y);
      s.z = fmaf(av[k], pk[k].z, s.z);
      s.w = fmaf(av[k], pk[k].w, s.w);
    }
    __builtin_nontemporal_store(s, (float4v*)(out + (size_t)n * 128 + c4));
  }
}

// ----------------------------------------------------------------
extern "C" void kernel_launch(void* const* d_in, const int* in_sizes, int n_in,
                              void* d_out, int out_size, void* d_ws, size_t ws_size,
                              hipStream_t stream) {
  const float* F    = (const float*)d_in[0];  // [N,128]
  const int*   erow = (const int*)d_in[1];    // [E]
  const int*   ecol = (const int*)d_in[2];    // [E]
  const float* eval_= (const float*)d_in[3];  // [E]
  const float* W    = (const float*)d_in[4];  // [16,128]
  const float* bias = (const float*)d_in[5];  // [16]

  int N = in_sizes[0] / 128;
  int E = in_sizes[1];

  float* out0 = (float*)d_out;                 // features_pooled [N,128]
  float* A    = out0 + (size_t)N * 128;        // assignments [N,16]
  float* loss = A + (size_t)N * 16;            // scalar
  float* ws   = (float*)d_ws;

  int GA = (N + 127) / 128;                    // k_assign grid (782)
  int GE = GE_BLOCKS;                          // 2048 edge-role blocks
  int GBp = GB_BLOCKS * 4;                     // 2048 bp partial rows

  // scratch inside the (not-yet-written) features_pooled output region
  __half* Ah  = (__half*)(out0 + OFF_AH);      // [N][16] fp16, 3.2 MB
  float*  csp = out0 + OFF_CSP;                // [GA][16]
  float*  ep  = out0 + OFF_EP;                 // [2048][18]
  float*  bp  = out0 + OFF_BP;                 // [2048][2048], 16.8 MB

  k_assign<<<GA, 256, 0, stream>>>(F, W, bias, A, Ah, csp, N);
  k_edge_nodeB<<<GE_BLOCKS + GB_BLOCKS, 256, 0, stream>>>(
      erow, ecol, eval_, Ah, F, A, ep, bp, E, N);
  k_reduce<<<258, 256, 0, stream>>>(csp, ep, bp, ws, GA, GE, GBp);
  k_unpool<<<1280, 256, 0, stream>>>(A, ws, out0, loss, N);
}

// Round 6
// 241.704 us; speedup vs baseline: 1.0269x; 1.0205x over previous
//
#include <hip/hip_runtime.h>
#include <hip/hip_fp16.h>
#include <math.h>

// ws float layout (header only):
//  [0] E_sum  [1] tr_gp  [2..17] m[16]  [18..33] cs[16]
//  [64..2112)   B[16][128]   (written by k_reduce)
// Scratch lives in the d_out features_pooled region (dead until k_unpool,
// which runs last and overwrites all of it):
//  out0[0      .. 800000)  Ah[N][16] fp16 shadow of assignments (3.2 MB)
//  out0[800000 .. 825008)  csp[GA][16] cluster-size partials (GA=1563, exact)
//  out0[825008 .. 861872)  ep[2048][18] edge partials (exactly fits)
//  out0[861872 .. +2048*2048) bp[2048][2048] B partial rows (16.8 MB)
// No atomics anywhere; nothing needs zero-init.
//
// EDGE ROOFLINE NOTE (R0/R2/R4/R5 evidence): divergent 16B gathers cost a
// stable ~2.5 cyc/lane-request/CU across 3 structural variants — TA/TCP
// address-processing wall. 12.8M requests is the floor; don't touch edge.

#define WS_ESUM 0
#define WS_TR   1
#define WS_M    2
#define WS_CS   18
#define WS_B    64

#define OFF_AH  0
#define OFF_CSP 800000
#define OFF_EP  825008
#define OFF_BP  861872

#define GE_BLOCKS 2048   // edge role blocks in fused kernel
#define GB_BLOCKS 512    // nodeB role blocks (4 waves -> 2048 partial rows)

typedef int   int4v   __attribute__((ext_vector_type(4)));
typedef float float2v __attribute__((ext_vector_type(2)));
typedef float float4v __attribute__((ext_vector_type(4)));

// ---------------------------------------------------------------- k_assign
// v3: 8 lanes/node (p covers 16 channels), 2 nodes/thread, 64 nodes/block,
// 1563 blocks -> 6252 waves (76% occupancy vs v2's 37%: v2 was grid-starved
// at 3 waves/SIMD; R0 counter OccupancyPercent=31 was the tell).
// Conflict-free LDS: Ws[k][p][20] — p*20 mod 32 = {0,20,8,28,16,4,24,12},
// so the 8 octets' float4 reads tile all 32 banks exactly once; the 8 lanes
// within an octet read the same address (broadcast).
__global__ __launch_bounds__(256) void k_assign(
    const float* __restrict__ F, const float* __restrict__ W,
    const float* __restrict__ bias, float* __restrict__ A,
    __half* __restrict__ Ah, float* __restrict__ csp, int N) {
  __shared__ float Ws[16 * 160];   // [k][p][20], 10240 B
  __shared__ float csred[4][16];
  int t = threadIdx.x;
#pragma unroll
  for (int i = 0; i < 8; i++) {
    int idx = t + 256 * i;         // 2048 = 16*128 elements
    int k = idx >> 7, r = idx & 127;
    Ws[k * 160 + (r >> 4) * 20 + (r & 15)] = W[idx];
  }
  __syncthreads();

  int p = t & 7;                   // octet part: channels p*16 .. p*16+15
  int slot = t >> 3;               // node slot (0..31)
  int n0 = blockIdx.x * 64 + slot;
  int n1 = n0 + 32;
  bool act0 = (n0 < N), act1 = (n1 < N);
  int n0c = act0 ? n0 : (N - 1);   // clamp: always-in-bounds loads
  int n1c = act1 ? n1 : (N - 1);

  float a0[16], a1[16];
#pragma unroll
  for (int k = 0; k < 16; k++) { a0[k] = 0.f; a1[k] = 0.f; }

  const float4* f0 = (const float4*)(F + (size_t)n0c * 128 + p * 16);
  const float4* f1 = (const float4*)(F + (size_t)n1c * 128 + p * 16);
#pragma unroll
  for (int i = 0; i < 4; i++) {
    float4 x0 = f0[i];
    float4 x1 = f1[i];
#pragma unroll
    for (int k = 0; k < 16; k++) {
      float4 w = *(const float4*)(&Ws[k * 160 + p * 20 + i * 4]);
      a0[k] = fmaf(x0.x, w.x, a0[k]);
      a0[k] = fmaf(x0.y, w.y, a0[k]);
      a0[k] = fmaf(x0.z, w.z, a0[k]);
      a0[k] = fmaf(x0.w, w.w, a0[k]);
      a1[k] = fmaf(x1.x, w.x, a1[k]);
      a1[k] = fmaf(x1.y, w.y, a1[k]);
      a1[k] = fmaf(x1.z, w.z, a1[k]);
      a1[k] = fmaf(x1.w, w.w, a1[k]);
    }
  }

  // reduce across the 8 lanes of the octet (xor 1,2,4 stays in-group)
#pragma unroll
  for (int k = 0; k < 16; k++) {
    a0[k] += __shfl_xor(a0[k], 1, 64);
    a0[k] += __shfl_xor(a0[k], 2, 64);
    a0[k] += __shfl_xor(a0[k], 4, 64);
    a1[k] += __shfl_xor(a1[k], 1, 64);
    a1[k] += __shfl_xor(a1[k], 2, 64);
    a1[k] += __shfl_xor(a1[k], 4, 64);
  }

#pragma unroll
  for (int k = 0; k < 16; k++) { a0[k] += bias[k]; a1[k] += bias[k]; }

  // softmax (both nodes, all 8 p-lanes redundantly)
  float mx0 = a0[0], mx1 = a1[0];
#pragma unroll
  for (int k = 1; k < 16; k++) { mx0 = fmaxf(mx0, a0[k]); mx1 = fmaxf(mx1, a1[k]); }
  float s0 = 0.f, s1 = 0.f;
#pragma unroll
  for (int k = 0; k < 16; k++) {
    a0[k] = __expf(a0[k] - mx0); s0 += a0[k];
    a1[k] = __expf(a1[k] - mx1); s1 += a1[k];
  }
  float inv0 = 1.0f / s0, inv1 = 1.0f / s1;
#pragma unroll
  for (int k = 0; k < 16; k++) { a0[k] *= inv0; a1[k] *= inv1; }

  // A writes: p0..3 cover n0's quarters, p4..7 cover n1's quarters
  if (p < 4) {
    if (act0)
      ((float4*)(A + (size_t)n0 * 16))[p] =
          make_float4(a0[p * 4 + 0], a0[p * 4 + 1], a0[p * 4 + 2], a0[p * 4 + 3]);
  } else {
    int q = p - 4;
    if (act1)
      ((float4*)(A + (size_t)n1 * 16))[q] =
          make_float4(a1[q * 4 + 0], a1[q * 4 + 1], a1[q * 4 + 2], a1[q * 4 + 3]);
  }

  // fp16 shadow: p==0/1 write n0 halves, p==2/3 write n1 halves
  if (p == 0 && act0) {
    __half2 hh[4];
    hh[0].x = __float2half_rn(a0[0]); hh[0].y = __float2half_rn(a0[1]);
    hh[1].x = __float2half_rn(a0[2]); hh[1].y = __float2half_rn(a0[3]);
    hh[2].x = __float2half_rn(a0[4]); hh[2].y = __float2half_rn(a0[5]);
    hh[3].x = __float2half_rn(a0[6]); hh[3].y = __float2half_rn(a0[7]);
    *(uint4*)(Ah + (size_t)n0 * 16) = *(uint4*)hh;
  } else if (p == 1 && act0) {
    __half2 hh[4];
    hh[0].x = __float2half_rn(a0[8]);  hh[0].y = __float2half_rn(a0[9]);
    hh[1].x = __float2half_rn(a0[10]); hh[1].y = __float2half_rn(a0[11]);
    hh[2].x = __float2half_rn(a0[12]); hh[2].y = __float2half_rn(a0[13]);
    hh[3].x = __float2half_rn(a0[14]); hh[3].y = __float2half_rn(a0[15]);
    *(uint4*)(Ah + (size_t)n0 * 16 + 8) = *(uint4*)hh;
  } else if (p == 2 && act1) {
    __half2 hh[4];
    hh[0].x = __float2half_rn(a1[0]); hh[0].y = __float2half_rn(a1[1]);
    hh[1].x = __float2half_rn(a1[2]); hh[1].y = __float2half_rn(a1[3]);
    hh[2].x = __float2half_rn(a1[4]); hh[2].y = __float2half_rn(a1[5]);
    hh[3].x = __float2half_rn(a1[6]); hh[3].y = __float2half_rn(a1[7]);
    *(uint4*)(Ah + (size_t)n1 * 16) = *(uint4*)hh;
  } else if (p == 3 && act1) {
    __half2 hh[4];
    hh[0].x = __float2half_rn(a1[8]);  hh[0].y = __float2half_rn(a1[9]);
    hh[1].x = __float2half_rn(a1[10]); hh[1].y = __float2half_rn(a1[11]);
    hh[2].x = __float2half_rn(a1[12]); hh[2].y = __float2half_rn(a1[13]);
    hh[3].x = __float2half_rn(a1[14]); hh[3].y = __float2half_rn(a1[15]);
    *(uint4*)(Ah + (size_t)n1 * 16 + 8) = *(uint4*)hh;
  }

  // cluster-size partials: p==0 contributes n0, p==4 contributes n1
  int lane = t & 63, wid = t >> 6;
#pragma unroll
  for (int k = 0; k < 16; k++) {
    float v = 0.f;
    if (p == 0 && act0) v += a0[k];
    if (p == 4 && act1) v += a1[k];
    for (int off = 32; off; off >>= 1) v += __shfl_xor(v, off, 64);
    if (lane == 0) csred[wid][k] = v;
  }
  __syncthreads();
  if (t < 16)
    csp[(size_t)blockIdx.x * 16 + t] =
        csred[0][t] + csred[1][t] + csred[2][t] + csred[3][t];
}

// ---------------------------------------------------------------- fused
// k_edge_nodeB (UNCHANGED — edge role at the TA request wall):
//  4 edge : 1 nodeB block interleave; edge = pair-split (2 lanes/edge, 16B
//  gathers); nodeB = wave-owns-nodes, private bp partial row.
union H2F4 { float4 f4; __half2 h2[4]; };

__device__ __forceinline__ void pair_body(
    const __half* __restrict__ Ah, const int* __restrict__ row,
    const int* __restrict__ col, const float* __restrict__ val,
    int e, int par, float& eS, float& tr, float* m) {
  int   r = __builtin_nontemporal_load(row + e);
  int   c = __builtin_nontemporal_load(col + e);
  float v = __builtin_nontemporal_load(val + e);
  const float4* pc = (const float4*)(Ah + ((size_t)c << 4) + (par << 3));
  const float4* pr = (const float4*)(Ah + ((size_t)r << 4) + (par << 3));
  H2F4 uc, ur;
  uc.f4 = *pc;
  ur.f4 = *pr;
  float cf[8], rf[8];
#pragma unroll
  for (int j = 0; j < 4; j++) {
    float2 f;
    f = __half22float2(uc.h2[j]); cf[2 * j] = f.x; cf[2 * j + 1] = f.y;
    f = __half22float2(ur.h2[j]); rf[2 * j] = f.x; rf[2 * j + 1] = f.y;
  }
  eS += v;
  float d = 0.f;
#pragma unroll
  for (int k = 0; k < 8; k++) {
    m[k] = fmaf(v, cf[k], m[k]);
    d = fmaf(rf[k], cf[k], d);
  }
  tr = fmaf(v, d, tr);
}

__global__ __launch_bounds__(256, 8) void k_edge_nodeB(
    const int* __restrict__ row, const int* __restrict__ col,
    const float* __restrict__ val, const __half* __restrict__ Ah,
    const float* __restrict__ F, const float* __restrict__ A,
    float* __restrict__ ep, float* __restrict__ bp, int E, int N) {
  __shared__ float red[4][18];
  int b = blockIdx.x;
  int t = threadIdx.x;
  bool isNode = ((b % 5) == 4);

  if (!isNode) {
    // ---------------- edge role: eb in [0, GE_BLOCKS)
    int eb = b - b / 5;
    int par = t & 1;                       // cluster half
    float eS = 0.f, tr = 0.f;
    float m[8];
#pragma unroll
    for (int i = 0; i < 8; i++) m[i] = 0.f;

    int pid = eb * 128 + (t >> 1);         // global pair id
    const int P = GE_BLOCKS * 128;         // pairs total (262144)
    int e = pid;
    for (; e + P < E; e += 2 * P) {
      pair_body(Ah, row, col, val, e, par, eS, tr, m);
      pair_body(Ah, row, col, val, e + P, par, eS, tr, m);
    }
    for (; e < E; e += P)
      pair_body(Ah, row, col, val, e, par, eS, tr, m);

    // parity-preserving reduce for m (offsets 32..2)
#pragma unroll
    for (int i = 0; i < 8; i++) {
      float v = m[i];
      v += __shfl_xor(v, 32, 64);
      v += __shfl_xor(v, 16, 64);
      v += __shfl_xor(v, 8, 64);
      v += __shfl_xor(v, 4, 64);
      v += __shfl_xor(v, 2, 64);
      m[i] = v;
    }
    // full reduce for eS, tr
    for (int off = 32; off; off >>= 1) {
      eS += __shfl_xor(eS, off, 64);
      tr += __shfl_xor(tr, off, 64);
    }
    int lane = t & 63, wid = t >> 6;
    if (lane == 0) {
      red[wid][0] = eS * 0.5f;             // each edge counted by both lanes
      red[wid][1] = tr;
#pragma unroll
      for (int i = 0; i < 8; i++) red[wid][2 + i] = m[i];
    } else if (lane == 1) {
#pragma unroll
      for (int i = 0; i < 8; i++) red[wid][10 + i] = m[i];
    }
    __syncthreads();
    if (t < 18)
      ep[(size_t)eb * 18 + t] =
          red[0][t] + red[1][t] + red[2][t] + red[3][t];
  } else {
    // ---------------- nodeB role: nb in [0, GB_BLOCKS)
    int nb = b / 5;
    int lane = t & 63;             // channel pair: c = 2*lane, 2*lane+1
    int wid = t >> 6;              // 0..3 — wave owns its own node stream

    float2 acc[16];
#pragma unroll
    for (int k = 0; k < 16; k++) acc[k] = make_float2(0.f, 0.f);

    const float2v* F2 = (const float2v*)F;
    const float4* A4 = (const float4*)A;
    const int stride = GB_BLOCKS * 4;
    for (int n = nb * 4 + wid; n < N; n += stride) {
      float2v f = __builtin_nontemporal_load(&F2[(size_t)n * 64 + lane]);
      float4 a0 = A4[(size_t)n * 4 + 0];
      float4 a1 = A4[(size_t)n * 4 + 1];
      float4 a2 = A4[(size_t)n * 4 + 2];
      float4 a3 = A4[(size_t)n * 4 + 3];
      float av[16] = {a0.x, a0.y, a0.z, a0.w, a1.x, a1.y, a1.z, a1.w,
                      a2.x, a2.y, a2.z, a2.w, a3.x, a3.y, a3.z, a3.w};
#pragma unroll
      for (int k = 0; k < 16; k++) {
        acc[k].x = fmaf(av[k], f.x, acc[k].x);
        acc[k].y = fmaf(av[k], f.y, acc[k].y);
      }
    }
    // each wave writes its own partial row — no reduction needed
    float* myrow = bp + (size_t)(nb * 4 + wid) * 2048;
#pragma unroll
    for (int k = 0; k < 16; k++)
      *(float2*)&myrow[k * 128 + lane * 2] = acc[k];
  }
}

// ---------------------------------------------------------------- k_reduce
// 258 blocks. GB = 2048 partial rows. (unchanged)
__global__ __launch_bounds__(256) void k_reduce(
    const float* __restrict__ csp, const float* __restrict__ ep,
    const float* __restrict__ bp, float* __restrict__ ws,
    int GA, int GE, int GB) {
  __shared__ float L[256];
  int t = threadIdx.x;
  int b = blockIdx.x;
  if (b < 256) {
    int cell = b * 8 + (t & 7);
    int seg = t >> 3;                      // 0..31
    float s0 = 0.f, s1 = 0.f, s2 = 0.f, s3 = 0.f;
    int g = seg;
    for (; g + 96 < GB; g += 128) {
      s0 += bp[(size_t)g * 2048 + cell];
      s1 += bp[(size_t)(g + 32) * 2048 + cell];
      s2 += bp[(size_t)(g + 64) * 2048 + cell];
      s3 += bp[(size_t)(g + 96) * 2048 + cell];
    }
    for (; g < GB; g += 32) s0 += bp[(size_t)g * 2048 + cell];
    L[t] = (s0 + s1) + (s2 + s3);
    __syncthreads();
    if (t < 8) {
      float tot = 0.f;
#pragma unroll
      for (int s = 0; s < 32; s++) tot += L[s * 8 + t];
      ws[WS_B + b * 8 + t] = tot;
    }
  } else if (b == 256) {
    int n = GE * 18;
    float s0 = 0.f, s1 = 0.f, s2 = 0.f, s3 = 0.f;
    if (t < 252) {
      int f = t;
      for (; f + 756 < n; f += 1008) {
        s0 += ep[f]; s1 += ep[f + 252]; s2 += ep[f + 504]; s3 += ep[f + 756];
      }
      for (; f < n; f += 252) s0 += ep[f];
    }
    L[t] = (s0 + s1) + (s2 + s3);
    __syncthreads();
    if (t < 18) {
      float tot = 0.f;
#pragma unroll
      for (int j = 0; j < 14; j++) tot += L[j * 18 + t];
      ws[t] = tot;                        // E_sum, tr, m[16]
    }
  } else {
    int n = GA * 16;
    float s0 = 0.f, s1 = 0.f, s2 = 0.f, s3 = 0.f;
    int f = t;
    for (; f + 768 < n; f += 1024) {
      s0 += csp[f]; s1 += csp[f + 256]; s2 += csp[f + 512]; s3 += csp[f + 768];
    }
    for (; f < n; f += 256) s0 += csp[f];
    L[t] = (s0 + s1) + (s2 + s3);
    __syncthreads();
    if (t < 16) {
      float tot = 0.f;
#pragma unroll
      for (int j = 0; j < 16; j++) tot += L[j * 16 + t];
      ws[WS_CS + t] = tot;
    }
  }
}

// ---------------------------------------------------------------- k_unpool
// out[n,c] = sum_k A[n,k] * P2[k,c]   (runs LAST — overwrites scratch)
// finalize folded in; P2 in registers; nontemporal float4 stores.
// v4: grid 2048 (8 blocks/CU = 100% occupancy, was 62%).
__global__ __launch_bounds__(256) void k_unpool(
    const float* __restrict__ A, float* __restrict__ ws,
    float* __restrict__ out, float* __restrict__ loss_out, int N) {
  __shared__ float Ps[2048];
  __shared__ float invcs[16];
  int t = threadIdx.x;
  if (t < 16) invcs[t] = 1.0f / ws[WS_CS + t];
  __syncthreads();
  const float scale = 1.0507009873554805f;
  const float alpha = 1.6732632423543772f;
#pragma unroll
  for (int i = 0; i < 8; i++) {
    int idx = t + 256 * i;
    int k = idx >> 7;
    float x = ws[WS_B + idx] * invcs[k];
    float s = (x > 0.f) ? scale * x : scale * alpha * expm1f(x);
    Ps[idx] = s * invcs[k];
  }
  __syncthreads();

  if (blockIdx.x == 0 && t == 0) {
    float Es = ws[WS_ESUM], tr = ws[WS_TR];
    float m2 = 0.f;
#pragma unroll
    for (int i = 0; i < 16; i++) m2 += ws[WS_M + i] * ws[WS_M + i];
    float spectral = -(tr - m2 / (2.0f * Es)) / (2.0f * Es);
    float coll = 0.f;
    float tgt = (float)N / 16.0f;
#pragma unroll
    for (int i = 0; i < 16; i++) coll += fabsf(ws[WS_CS + i] - tgt);
    coll = coll / (float)N * (4.0f / 3.0f / 2.0f);  // sk/(sk-1)/2, sk=4
    loss_out[0] = spectral + coll;
  }

  int c4 = (t & 31) << 2;          // channel base (0,4,...,124)
  int sub = t >> 5;                // 0..7 (node within group)
  float4 pk[16];
#pragma unroll
  for (int k = 0; k < 16; k++) pk[k] = *(const float4*)&Ps[k * 128 + c4];

  int stride = gridDim.x * 8;
  for (int n = blockIdx.x * 8 + sub; n < N; n += stride) {
    const float4* a4 = (const float4*)(A + (size_t)n * 16);
    float4 a0 = a4[0], a1 = a4[1], a2 = a4[2], a3 = a4[3];
    float av[16] = {a0.x, a0.y, a0.z, a0.w, a1.x, a1.y, a1.z, a1.w,
                    a2.x, a2.y, a2.z, a2.w, a3.x, a3.y, a3.z, a3.w};
    float4v s = {0.f, 0.f, 0.f, 0.f};
#pragma unroll
    for (int k = 0; k < 16; k++) {
      s.x = fmaf(av[k], pk[k].x, s.x);
      s.y = fmaf(av[k], pk[k].y, s.y);
      s.z = fmaf(av[k], pk[k].z, s.z);
      s.w = fmaf(av[k], pk[k].w, s.w);
    }
    __builtin_nontemporal_store(s, (float4v*)(out + (size_t)n * 128 + c4));
  }
}

// ----------------------------------------------------------------
extern "C" void kernel_launch(void* const* d_in, const int* in_sizes, int n_in,
                              void* d_out, int out_size, void* d_ws, size_t ws_size,
                              hipStream_t stream) {
  const float* F    = (const float*)d_in[0];  // [N,128]
  const int*   erow = (const int*)d_in[1];    // [E]
  const int*   ecol = (const int*)d_in[2];    // [E]
  const float* eval_= (const float*)d_in[3];  // [E]
  const float* W    = (const float*)d_in[4];  // [16,128]
  const float* bias = (const float*)d_in[5];  // [16]

  int N = in_sizes[0] / 128;
  int E = in_sizes[1];

  float* out0 = (float*)d_out;                 // features_pooled [N,128]
  float* A    = out0 + (size_t)N * 128;        // assignments [N,16]
  float* loss = A + (size_t)N * 16;            // scalar
  float* ws   = (float*)d_ws;

  int GA = (N + 63) / 64;                      // k_assign grid (1563)
  int GE = GE_BLOCKS;                          // 2048 edge-role blocks
  int GBp = GB_BLOCKS * 4;                     // 2048 bp partial rows

  // scratch inside the (not-yet-written) features_pooled output region
  __half* Ah  = (__half*)(out0 + OFF_AH);      // [N][16] fp16, 3.2 MB
  float*  csp = out0 + OFF_CSP;                // [GA][16] = 25008 floats exact
  float*  ep  = out0 + OFF_EP;                 // [2048][18]
  float*  bp  = out0 + OFF_BP;                 // [2048][2048], 16.8 MB

  k_assign<<<GA, 256, 0, stream>>>(F, W, bias, A, Ah, csp, N);
  k_edge_nodeB<<<GE_BLOCKS + GB_BLOCKS, 256, 0, stream>>>(
      erow, ecol, eval_, Ah, F, A, ep, bp, E, N);
  k_reduce<<<258, 256, 0, stream>>>(csp, ep, bp, ws, GA, GE, GBp);
  k_unpool<<<2048, 256, 0, stream>>>(A, ws, out0, loss, N);
}